// Round 4
// baseline (247.606 us; speedup 1.0000x reference)
//
#include <hip/hip_runtime.h>
#include <stdint.h>

#define DECAY 0.99f
#define OMDECAY 0.01f
#define EPSV 1e-5f

// Problem: z (32,256,32,32) fp32; tokens N=32768, D=256, K=1024 codes.
// out (floats): zq[0,8388608) idx[8388608,8421376) loss[8421376]
//               new_embed[8421377,..) new_cs[8683521,..) new_ea[8684545,..)
//   best64 scratch overlays new_embed region at out+8421378 (65536 dwords),
//   dead before finalize_embed overwrites it.
//   znorm stash overlays out_idx region (prep writes ||z_t||^2 there;
//   merge_zq reads it before overwriting with the code index).
// ws (dwords):
//   B_hi32   0        (131072)   1024x256 f16 FRAGMENT-PACKED  } es (262144 fp32)
//   B_lo32   131072   (131072)     (see pack below)            } reused after vq_mfma
//   A_hi32   262144   (4194304)  32768x256 f16, token-major
//   A_lo32   4456448  (4194304)
//   perm     8650752  (32768)    int, tokens sorted by code
//   offsets  8683520  (1024)     int, segment starts
//   cursor   8684544  (1024)     int, atomic cursors
//   cs       8912896  (1024)     fp32 histogram
//   loss     8913920  (1024, 1 used)
//   enorm    8914944  (1024)
//   csnorm   8915968  (1024)
//
// B fragment pack (dword units): element (code k, dim d) ->
//   dword[ ((k>>4)*8 + (d>>5))*256 + (k&15)*16 + ((d&31)>>3)*4 + ((d&7)>>1) ],
//   f16 slot (d&1).  A wave's per-(j,step) B load is one CONTIGUOUS 1 KB burst.

typedef _Float16 half8 __attribute__((ext_vector_type(8)));
typedef float floatx4 __attribute__((ext_vector_type(4)));

typedef __attribute__((address_space(1))) const uint32_t gu32;
typedef __attribute__((address_space(3))) uint32_t lu32;

__device__ __forceinline__ void gld16(uint32_t* l, const uint32_t* g) {
    __builtin_amdgcn_global_load_lds((gu32*)g, (lu32*)l, 16, 0, 0);
}

__device__ __forceinline__ uint32_t pack_hl(float v) {
    _Float16 h = (_Float16)v;
    _Float16 lo = (_Float16)(v - (float)h);
    return (uint32_t)__builtin_bit_cast(unsigned short, h) |
           ((uint32_t)__builtin_bit_cast(unsigned short, lo) << 16);
}

// monotone float -> uint32 (ascending order preserved)
__device__ __forceinline__ unsigned int encf(float s) {
    unsigned int b = __builtin_bit_cast(unsigned int, s);
    return (b & 0x80000000u) ? ~b : (b | 0x80000000u);
}
// inverse of encf
__device__ __forceinline__ float decf(unsigned int u) {
    unsigned int b = (u & 0x80000000u) ? (u ^ 0x80000000u) : ~u;
    return __builtin_bit_cast(float, b);
}

// ---- fused prep: blocks [0,1024) = split_z (+znorm) ; [1024,2048) = prep_embed ----
__global__ void prep_fused(const float* __restrict__ z,
                           uint32_t* __restrict__ A_hi32,
                           uint32_t* __restrict__ A_lo32,
                           const float* __restrict__ embed,
                           unsigned short* __restrict__ B_hi16,
                           unsigned short* __restrict__ B_lo16,
                           float* __restrict__ enorm,
                           float* __restrict__ cs /* + loss contiguous */,
                           uint32_t* __restrict__ b64i,
                           float* __restrict__ znstash) {
    __shared__ uint32_t sp[32 * 258];
    __shared__ float znacc[4][32];
    const int bx = blockIdx.x;
    const int tid = threadIdx.x;
    const int lane = tid & 63;
    const int wv = tid >> 6;

    if (bx < 1024) {
        // ---- split_z: z (b,d,h,w) -> token-major f16 hi/lo A[t][d]; + ||z||^2 ----
        const int t0  = bx * 32;
        const int b   = t0 >> 10;
        const int hw0 = t0 & 1023;
        const int l32 = lane & 31;
        const int dh  = lane >> 5;
        float zn = 0.f;
        for (int dp = wv; dp < 128; dp += 4) {
            int dd = dp * 2 + dh;
            float v = z[b * 262144 + dd * 1024 + hw0 + l32];
            sp[l32 * 258 + dd] = pack_hl(v);
            zn += v * v;
        }
        zn += __shfl_xor(zn, 32);           // combine dh=0/1 partners
        if (lane < 32) znacc[wv][lane] = zn;
        __syncthreads();
        if (tid < 32)
            znstash[t0 + tid] = znacc[0][tid] + znacc[1][tid] +
                                znacc[2][tid] + znacc[3][tid];
        for (int r = wv; r < 32; r += 4) {
#pragma unroll
            for (int h2 = 0; h2 < 2; ++h2) {
                int dpair = h2 * 64 + lane;
                uint32_t u0 = sp[r * 258 + 2 * dpair];
                uint32_t u1 = sp[r * 258 + 2 * dpair + 1];
                A_hi32[(t0 + r) * 128 + dpair] = (u0 & 0xffffu) | (u1 << 16);
                A_lo32[(t0 + r) * 128 + dpair] = (u0 >> 16) | (u1 & 0xffff0000u);
            }
        }
    } else {
        // ---- prep_embed: fragment-pack embed + enorm + zero cs/loss + best64 init ----
        float* ws4 = (float*)sp;
        const int k = bx - 1024;
        const int d = tid;
        float v = embed[k * 256 + d];
        _Float16 h = (_Float16)v;
        _Float16 lo = (_Float16)(v - (float)h);
        // fragment-packed ushort index
        const int c16 = k & 15, cg = k >> 4;
        const int dc = d >> 5, dl = d & 31;
        const int qq = dl >> 3, dw = (dl & 7) >> 1, hl = d & 1;
        const int us = ((cg * 8 + dc) * 256 + c16 * 16 + qq * 4 + dw) * 2 + hl;
        B_hi16[us] = __builtin_bit_cast(unsigned short, h);
        B_lo16[us] = __builtin_bit_cast(unsigned short, lo);
        float s = v * v;
        for (int off = 32; off > 0; off >>= 1) s += __shfl_down(s, off);
        if (lane == 0) ws4[wv] = s;
        __syncthreads();
        if (tid == 0) enorm[k] = ws4[0] + ws4[1] + ws4[2] + ws4[3];
        if (k < 256) b64i[k * 256 + tid] = 0xFFFFFFFFu;   // best64 = +inf keys
        if (k == 0) {
            for (int i = tid; i < 2048; i += 256) cs[i] = 0.f;   // cs + loss_sum
        }
    }
}

// ---- main: MFMA distance GEMM + argmin via packed atomicMin ----
// 2048 blocks = 512 token-groups(64 tok) x 4 code-quarters (256 codes).
// XCD-grouped decode keeps a token-group's 4 quarter-blocks on one XCD.
// Block: 4 waves, acc[4][4] per wave (64 f32) -> ~half the register state
// of round 3, targeting 3 blocks/CU (12 waves) so independent blocks fill
// each other's barrier/stage holes.  LDS holds only A (hi/lo, dbuf, 16 KiB).
// B streams global->reg (fragment-packed 1 KB bursts, register-dbuf).
// Counted vmcnt(10) = 2 A-gld16 + 8 B just issued; never 0 mid-loop.
// A-side XOR swizzle (source + read, linear gld_lds dest) keeps LDS
// conflict-free.  Accumulation order per (token,code) identical to r1-r3.
__global__ __launch_bounds__(256, 3) void vq_mfma(
    const uint32_t* __restrict__ A_hi32,
    const uint32_t* __restrict__ A_lo32,
    const uint32_t* __restrict__ B_hi32,
    const uint32_t* __restrict__ B_lo32,
    const float* __restrict__ enorm,
    unsigned long long* __restrict__ best64)
{
    __shared__ __align__(16) _Float16 Abuf[2][2][2048];  // [buf][hi/lo][64x32] 16 KiB

    const int lane = threadIdx.x & 63;
    const int w    = threadIdx.x >> 6;   // 0..3
    const int q    = lane >> 4;
    const int c16  = lane & 15;
    const int bb   = blockIdx.x;
    const int xcd  = bb & 7;
    const int slot = bb >> 3;
    const int g    = (slot >> 2) * 8 + xcd;   // token group 0..511
    const int cq   = slot & 3;                // code quarter 0..3
    const int t0   = g * 64;
    const int cb   = cq * 256;
    const int lane4 = lane >> 2;
    // source-side swizzle: chunk c of row r lands at LDS slot c ^ ((r>>1)&3)
    const int dd8s  = ((lane & 3) ^ ((lane >> 3) & 3)) * 8;
    const int qs    = q ^ ((c16 >> 1) & 3);

    // staging role: wave w stages matrix (w>>1), row-blocks (w&1)*2 + s
    const uint32_t* const sA = (w >> 1) ? A_lo32 : A_hi32;
    const int r16b = (w & 1) * 2;

    // per-wave code slice: codes cb + w*64 + j*16 + c16 (fragment-packed B)
    float en[4];
    const uint32_t* bph[4];
    const uint32_t* bpl[4];
#pragma unroll
    for (int j = 0; j < 4; ++j) {
        const int code = cb + w * 64 + j * 16 + c16;
        en[j]  = enorm[code];
        const int cgj = (cb >> 4) + w * 4 + j;
        bph[j] = B_hi32 + cgj * 2048 + c16 * 16 + q * 4;
        bpl[j] = B_lo32 + cgj * 2048 + c16 * 16 + q * 4;
    }

    floatx4 acc[4][4];
#pragma unroll
    for (int i = 0; i < 4; ++i)
#pragma unroll
        for (int j = 0; j < 4; ++j)
            acc[i][j] = (floatx4){0.f, 0.f, 0.f, 0.f};

    half8 bh[2][4], bl[2][4];

    auto STAGE_A = [&](int step) {
        uint32_t* dst = (uint32_t*)(&Abuf[step & 1][w >> 1][0]);
        const int srcoff = (step * 32 + dd8s) >> 1;
#pragma unroll
        for (int s = 0; s < 2; ++s) {
            const int r16 = r16b + s;
            gld16(dst + r16 * 256, sA + (t0 + r16 * 16 + lane4) * 128 + srcoff);
        }
    };
    auto LOAD_B = [&](int step, half8* h, half8* l) {
#pragma unroll
        for (int j = 0; j < 4; ++j) {
            h[j] = *(const half8*)(bph[j] + step * 256);
            l[j] = *(const half8*)(bpl[j] + step * 256);
        }
    };

    STAGE_A(0);
    LOAD_B(0, bh[0], bl[0]);

#pragma unroll
    for (int dc = 0; dc < 8; ++dc) {
        if (dc < 7) {
            STAGE_A(dc + 1);
            LOAD_B(dc + 1, bh[(dc + 1) & 1], bl[(dc + 1) & 1]);
            // 10 ops just issued -> waiting to 10 drains all of step dc
            asm volatile("s_waitcnt vmcnt(10)" ::: "memory");
        } else {
            asm volatile("s_waitcnt vmcnt(0)" ::: "memory");
        }
        __builtin_amdgcn_s_barrier();   // all waves' A(dc) staged
        asm volatile("" ::: "memory");

        const _Float16* pH = &Abuf[dc & 1][0][0];
        const _Float16* pL = &Abuf[dc & 1][1][0];
        __builtin_amdgcn_s_setprio(1);
#pragma unroll
        for (int i = 0; i < 4; ++i) {
            const int off = (i * 16 + c16) * 32 + qs * 8;
            half8 aH = *(const half8*)(pH + off);
            half8 aL = *(const half8*)(pL + off);
#pragma unroll
            for (int j = 0; j < 4; ++j) {
                acc[i][j] = __builtin_amdgcn_mfma_f32_16x16x32_f16(aH, bh[dc & 1][j], acc[i][j], 0, 0, 0);
                acc[i][j] = __builtin_amdgcn_mfma_f32_16x16x32_f16(aH, bl[dc & 1][j], acc[i][j], 0, 0, 0);
                acc[i][j] = __builtin_amdgcn_mfma_f32_16x16x32_f16(aL, bh[dc & 1][j], acc[i][j], 0, 0, 0);
            }
        }
        __builtin_amdgcn_s_setprio(0);
        asm volatile("" ::: "memory");
        if (dc < 7) __builtin_amdgcn_s_barrier();  // buf reads done before
                                                   // next iter's overwrite
    }

    // ---- epilogue: packed u64 (encf(score)<<32 | code) argmin ----
    unsigned long long best[16];
#pragma unroll
    for (int sl = 0; sl < 16; ++sl) best[sl] = ~0ULL;
#pragma unroll
    for (int j = 0; j < 4; ++j) {
        const unsigned int code = (unsigned int)(cb + w * 64 + j * 16 + c16);
        const float enj = en[j];
#pragma unroll
        for (int i = 0; i < 4; ++i)
#pragma unroll
            for (int r = 0; r < 4; ++r) {
                float sc = enj - 2.0f * acc[i][j][r];
                unsigned long long key =
                    ((unsigned long long)encf(sc) << 32) | code;
                int sl = i * 4 + r;
                if (key < best[sl]) best[sl] = key;
            }
    }
    // butterfly min across the 16 c16-lanes sharing each token
#pragma unroll
    for (int sl = 0; sl < 16; ++sl) {
        unsigned long long v = best[sl];
#pragma unroll
        for (int mm = 1; mm < 16; mm <<= 1) {
            unsigned long long o = __shfl_xor(v, mm);
            if (o < v) v = o;
        }
        if (c16 == sl) {
            int tok = t0 + (sl >> 2) * 16 + q * 4 + (sl & 3);
            atomicMin(&best64[tok], v);
        }
    }
}

// ---- merge: decode best64 -> idx/cs/loss, write zq via float4 gathers ----
// loss = sum_t ( ||z_t||^2 + score_t ), score decoded exactly from the key.
__global__ __launch_bounds__(256) void merge_zq(
    const unsigned long long* __restrict__ best64,
    const float* __restrict__ embed,
    float* __restrict__ out_zq,
    float* __restrict__ out_idx /* = znorm stash, read before overwrite */,
    float* __restrict__ cs,
    float* __restrict__ loss_sum)
{
    __shared__ int sidx[64];
    const int tid = threadIdx.x;
    const int lane = tid & 63;
    const int w = tid >> 6;
    const int t0 = blockIdx.x * 64;

    if (tid < 64) {
        unsigned long long key = best64[t0 + tid];
        int code = (int)(unsigned int)(key & 0xffffffffULL);
        float sc = decf((unsigned int)(key >> 32));
        float zn = out_idx[t0 + tid];       // znorm stash (read first!)
        sidx[tid] = code;
        out_idx[t0 + tid] = (float)code;
        atomicAdd(&cs[code], 1.0f);
        float val = zn + sc;                 // ~ ||z_t - e_code||^2
        for (int off = 32; off > 0; off >>= 1) val += __shfl_down(val, off);
        if (lane == 0) atomicAdd(loss_sum, val);
    }
    __syncthreads();

    const int b_idx = t0 >> 10;
    const int hw0   = t0 & 1023;
    const int zbase = b_idx * 262144 + hw0;
    const int ka = sidx[lane];
    const float* erow = embed + ka * 256;
    for (int dq = w; dq < 64; dq += 4) {
        float4 e4 = *(const float4*)(erow + dq * 4);
        out_zq[zbase + (dq * 4 + 0) * 1024 + lane] = e4.x;
        out_zq[zbase + (dq * 4 + 1) * 1024 + lane] = e4.y;
        out_zq[zbase + (dq * 4 + 2) * 1024 + lane] = e4.z;
        out_zq[zbase + (dq * 4 + 3) * 1024 + lane] = e4.w;
    }
}

// ---- finalize: loss, new_cluster, csnorm, prefix-scan (wave shuffles) ----
__global__ void vq_finalize_small(const float* __restrict__ cluster_size,
                                  const float* __restrict__ cs,
                                  const float* __restrict__ loss_sum,
                                  float* __restrict__ out_loss,
                                  float* __restrict__ out_ncs,
                                  float* __restrict__ csnorm,
                                  int* __restrict__ offsets,
                                  int* __restrict__ cursor)
{
    __shared__ float wsum[16];
    __shared__ float wncs[16];
    __shared__ float stot[1];
    const int k = threadIdx.x;
    const int lane = k & 63;
    const int wv = k >> 6;
    float cnt = cs[k];
    float ncs = cluster_size[k] * DECAY + OMDECAY * cnt;
    out_ncs[k] = ncs;
    float sc = cnt;
#pragma unroll
    for (int d = 1; d < 64; d <<= 1) {
        float up = __shfl_up(sc, d);
        if (lane >= d) sc += up;
    }
    if (lane == 63) wsum[wv] = sc;
    float ns = ncs;
    for (int off = 32; off > 0; off >>= 1) ns += __shfl_down(ns, off);
    if (lane == 0) wncs[wv] = ns;
    __syncthreads();
    if (wv == 0) {
        float v = (lane < 16) ? wsum[lane] : 0.f;
#pragma unroll
        for (int d = 1; d < 16; d <<= 1) {
            float up = __shfl_up(v, d);
            if (lane >= d) v += up;
        }
        if (lane < 16) wsum[lane] = v;
    } else if (wv == 1) {
        float t = (lane < 16) ? wncs[lane] : 0.f;
        for (int off = 32; off > 0; off >>= 1) t += __shfl_down(t, off);
        if (lane == 0) stot[0] = t;
    }
    __syncthreads();
    float incl = sc + (wv ? wsum[wv - 1] : 0.f);
    int excl = __float2int_rn(incl - cnt);
    offsets[k] = excl;
    cursor[k]  = excl;
    float n = stot[0];
    csnorm[k] = (ncs + EPSV) / (n + 1024.0f * EPSV) * n;
    if (k == 0) out_loss[0] = loss_sum[0] / 8388608.0f;
}

// ---- counting-sort scatter + es zeroing ----
__global__ void scatter_perm(const float* __restrict__ out_idx,
                             int* __restrict__ cursor,
                             int* __restrict__ perm,
                             float* __restrict__ es)
{
    int t = blockIdx.x * 256 + threadIdx.x;
#pragma unroll
    for (int i = 0; i < 8; ++i) es[t + i * 32768] = 0.f;
    int code = (int)out_idx[t];
    int pos = atomicAdd(&cursor[code], 1);
    perm[pos] = t;
}

// ---- chunked segmented sum over the SORTED token list ----
__global__ void es_sum(const uint32_t* __restrict__ A_hi32,
                       const uint32_t* __restrict__ A_lo32,
                       const int* __restrict__ perm,
                       const float* __restrict__ out_idx,
                       float* __restrict__ es)
{
    __shared__ int sperm[32];
    __shared__ int scode[32];
    const int base = blockIdx.x * 32;
    const int tid = threadIdx.x;
    const int j = tid & 127;
    const uint32_t* __restrict__ A = (tid >> 7) ? A_lo32 : A_hi32;
    if (tid < 32) {
        int t = perm[base + tid];
        sperm[tid] = t;
        scode[tid] = (int)out_idx[t];
    }
    __syncthreads();

    float s0 = 0.f, s1 = 0.f;
    int cur = scode[0];
    uint32_t pu[2];
    pu[0] = A[sperm[0] * 128 + j];
    pu[1] = A[sperm[1] * 128 + j];
#pragma unroll
    for (int i = 0; i < 32; ++i) {
        uint32_t u = pu[i & 1];
        if (i + 2 < 32) pu[i & 1] = A[sperm[i + 2] * 128 + j];
        int code = scode[i];
        if (code != cur) {
            atomicAdd(&es[cur * 256 + 2 * j],     s0);
            atomicAdd(&es[cur * 256 + 2 * j + 1], s1);
            s0 = 0.f; s1 = 0.f; cur = code;
        }
        s0 += (float)__builtin_bit_cast(_Float16, (unsigned short)(u & 0xffffu));
        s1 += (float)__builtin_bit_cast(_Float16, (unsigned short)(u >> 16));
    }
    atomicAdd(&es[cur * 256 + 2 * j],     s0);
    atomicAdd(&es[cur * 256 + 2 * j + 1], s1);
}

// ---- EMA finalize for embed_avg / embed (overwrites best64 scratch) ----
__global__ void finalize_embed(const float* __restrict__ embed_avg,
                               const float* __restrict__ es,
                               const float* __restrict__ csnorm,
                               float* __restrict__ out_embed,
                               float* __restrict__ out_nea)
{
    int idx = blockIdx.x * 256 + threadIdx.x;
    int k = idx >> 8;
    float nea = embed_avg[idx] * DECAY + OMDECAY * es[idx];
    out_nea[idx] = nea;
    out_embed[idx] = nea / csnorm[k];
}

extern "C" void kernel_launch(void* const* d_in, const int* in_sizes, int n_in,
                              void* d_out, int out_size, void* d_ws, size_t ws_size,
                              hipStream_t stream) {
    const float* z            = (const float*)d_in[0];
    const float* embed        = (const float*)d_in[1];
    const float* cluster_size = (const float*)d_in[2];
    const float* embed_avg    = (const float*)d_in[3];
    float* out = (float*)d_out;
    uint32_t* ws32 = (uint32_t*)d_ws;

    uint32_t* B_hi32 = ws32 + 0;
    uint32_t* B_lo32 = ws32 + 131072;
    uint32_t* A_hi32 = ws32 + 262144;
    uint32_t* A_lo32 = ws32 + 4456448;
    int* perm        = (int*)(ws32 + 8650752);
    int* offsets     = (int*)(ws32 + 8683520);
    int* cursor      = (int*)(ws32 + 8684544);
    float* cs        = (float*)(ws32 + 8912896);
    float* loss_sum  = (float*)(ws32 + 8913920);
    float* enorm     = (float*)(ws32 + 8914944);
    float* csnorm    = (float*)(ws32 + 8915968);
    float* es        = (float*)(ws32 + 0);        // reuses B_hi/B_lo after vq_mfma
    // best64 scratch overlays the new_embed output region (8-byte aligned)
    unsigned long long* best64 = (unsigned long long*)(out + 8421378);
    float* znstash = out + 8388608;               // overlays out_idx region

    prep_fused<<<2048, 256, 0, stream>>>(z, A_hi32, A_lo32, embed,
                                         (unsigned short*)B_hi32,
                                         (unsigned short*)B_lo32, enorm, cs,
                                         (uint32_t*)best64, znstash);
    vq_mfma<<<2048, 256, 0, stream>>>(A_hi32, A_lo32, B_hi32, B_lo32, enorm, best64);
    merge_zq<<<512, 256, 0, stream>>>(best64, embed,
                                      out, out + 8388608, cs, loss_sum);
    vq_finalize_small<<<1, 1024, 0, stream>>>(cluster_size, cs, loss_sum,
                                              out + 8421376, out + 8683521, csnorm,
                                              offsets, cursor);
    scatter_perm<<<128, 256, 0, stream>>>(out + 8388608, cursor, perm, es);
    es_sum<<<1024, 256, 0, stream>>>(A_hi32, A_lo32, perm, out + 8388608, es);
    finalize_embed<<<1024, 256, 0, stream>>>(embed_avg, es, csnorm,
                                             out + 8421377, out + 8684545);
}

// Round 5
// 225.449 us; speedup vs baseline: 1.0983x; 1.0983x over previous
//
#include <hip/hip_runtime.h>
#include <stdint.h>

#define DECAY 0.99f
#define OMDECAY 0.01f
#define EPSV 1e-5f

// Problem: z (32,256,32,32) fp32; tokens N=32768, D=256, K=1024 codes.
// out (floats): zq[0,8388608) idx[8388608,8421376) loss[8421376]
//               new_embed[8421377,..) new_cs[8683521,..) new_ea[8684545,..)
//   best64 scratch overlays new_embed region at out+8421378 (65536 dwords),
//   dead before finalize_embed overwrites it.
//   znorm stash overlays out_idx region (prep writes ||z_t||^2 there;
//   merge_zq reads it before overwriting with the code index).
// ws (dwords):
//   B_hi32   0        (131072)   1024x256 f16 FRAGMENT-PACKED  } es (262144 fp32)
//   B_lo32   131072   (131072)     (see pack below)            } reused after vq_mfma
//   A_hi32   262144   (4194304)  32768x256 f16, token-major
//   A_lo32   4456448  (4194304)
//   perm     8650752  (32768)    int, tokens sorted by code
//   offsets  8683520  (1024)     int, segment starts
//   cursor   8684544  (1024)     int, atomic cursors
//   cs       8912896  (1024)     fp32 histogram
//   loss     8913920  (1024, 1 used)
//   enorm    8914944  (1024)
//   csnorm   8915968  (1024)
//
// B fragment pack (dword units): element (code k, dim d) ->
//   dword[ ((k>>4)*8 + (d>>5))*256 + (k&15)*16 + ((d&31)>>3)*4 + ((d&7)>>1) ],
//   f16 slot (d&1).  A wave's per-(j,step) B load is one CONTIGUOUS 1 KB burst.

typedef _Float16 half8 __attribute__((ext_vector_type(8)));
typedef float floatx4 __attribute__((ext_vector_type(4)));

typedef __attribute__((address_space(1))) const uint32_t gu32;
typedef __attribute__((address_space(3))) uint32_t lu32;

__device__ __forceinline__ void gld16(uint32_t* l, const uint32_t* g) {
    __builtin_amdgcn_global_load_lds((gu32*)g, (lu32*)l, 16, 0, 0);
}

__device__ __forceinline__ uint32_t pack_hl(float v) {
    _Float16 h = (_Float16)v;
    _Float16 lo = (_Float16)(v - (float)h);
    return (uint32_t)__builtin_bit_cast(unsigned short, h) |
           ((uint32_t)__builtin_bit_cast(unsigned short, lo) << 16);
}

// monotone float -> uint32 (ascending order preserved)
__device__ __forceinline__ unsigned int encf(float s) {
    unsigned int b = __builtin_bit_cast(unsigned int, s);
    return (b & 0x80000000u) ? ~b : (b | 0x80000000u);
}
// inverse of encf
__device__ __forceinline__ float decf(unsigned int u) {
    unsigned int b = (u & 0x80000000u) ? (u ^ 0x80000000u) : ~u;
    return __builtin_bit_cast(float, b);
}

// ---- fused prep: blocks [0,1024) = split_z (+znorm) ; [1024,2048) = prep_embed ----
__global__ void prep_fused(const float* __restrict__ z,
                           uint32_t* __restrict__ A_hi32,
                           uint32_t* __restrict__ A_lo32,
                           const float* __restrict__ embed,
                           unsigned short* __restrict__ B_hi16,
                           unsigned short* __restrict__ B_lo16,
                           float* __restrict__ enorm,
                           float* __restrict__ cs /* + loss contiguous */,
                           uint32_t* __restrict__ b64i,
                           float* __restrict__ znstash) {
    __shared__ uint32_t sp[32 * 258];
    __shared__ float znacc[4][32];
    const int bx = blockIdx.x;
    const int tid = threadIdx.x;
    const int lane = tid & 63;
    const int wv = tid >> 6;

    if (bx < 1024) {
        // ---- split_z: z (b,d,h,w) -> token-major f16 hi/lo A[t][d]; + ||z||^2 ----
        const int t0  = bx * 32;
        const int b   = t0 >> 10;
        const int hw0 = t0 & 1023;
        const int l32 = lane & 31;
        const int dh  = lane >> 5;
        float zn = 0.f;
        for (int dp = wv; dp < 128; dp += 4) {
            int dd = dp * 2 + dh;
            float v = z[b * 262144 + dd * 1024 + hw0 + l32];
            sp[l32 * 258 + dd] = pack_hl(v);
            zn += v * v;
        }
        zn += __shfl_xor(zn, 32);           // combine dh=0/1 partners
        if (lane < 32) znacc[wv][lane] = zn;
        __syncthreads();
        if (tid < 32)
            znstash[t0 + tid] = znacc[0][tid] + znacc[1][tid] +
                                znacc[2][tid] + znacc[3][tid];
        for (int r = wv; r < 32; r += 4) {
#pragma unroll
            for (int h2 = 0; h2 < 2; ++h2) {
                int dpair = h2 * 64 + lane;
                uint32_t u0 = sp[r * 258 + 2 * dpair];
                uint32_t u1 = sp[r * 258 + 2 * dpair + 1];
                A_hi32[(t0 + r) * 128 + dpair] = (u0 & 0xffffu) | (u1 << 16);
                A_lo32[(t0 + r) * 128 + dpair] = (u0 >> 16) | (u1 & 0xffff0000u);
            }
        }
    } else {
        // ---- prep_embed: fragment-pack embed + enorm + zero cs/loss + best64 init ----
        float* ws4 = (float*)sp;
        const int k = bx - 1024;
        const int d = tid;
        float v = embed[k * 256 + d];
        _Float16 h = (_Float16)v;
        _Float16 lo = (_Float16)(v - (float)h);
        // fragment-packed ushort index
        const int c16 = k & 15, cg = k >> 4;
        const int dc = d >> 5, dl = d & 31;
        const int qq = dl >> 3, dw = (dl & 7) >> 1, hl = d & 1;
        const int us = ((cg * 8 + dc) * 256 + c16 * 16 + qq * 4 + dw) * 2 + hl;
        B_hi16[us] = __builtin_bit_cast(unsigned short, h);
        B_lo16[us] = __builtin_bit_cast(unsigned short, lo);
        float s = v * v;
        for (int off = 32; off > 0; off >>= 1) s += __shfl_down(s, off);
        if (lane == 0) ws4[wv] = s;
        __syncthreads();
        if (tid == 0) enorm[k] = ws4[0] + ws4[1] + ws4[2] + ws4[3];
        if (k < 256) b64i[k * 256 + tid] = 0xFFFFFFFFu;   // best64 = +inf keys
        if (k == 0) {
            for (int i = tid; i < 2048; i += 256) cs[i] = 0.f;   // cs + loss_sum
        }
    }
}

// ---- main: MFMA distance GEMM + argmin via packed atomicMin ----
// 1024 blocks = 256 token-groups(128 tok) x 4 code-quarters (256 codes),
// XCD-grouped.  Round-3 geometry (4 waves, A-LDS dbuf 32 KiB, B reg-streamed
// from fragment-packed layout, 2 blocks/CU) with the K-loop ported to a
// 4-SUB-PHASE schedule (T3+T4): per dc-step, 4 phases of
//   {4 ds_read_b128 || issue next-step loads -> barrier -> setprio ->
//    24 MFMA -> setprio -> barrier}
// Issue order per step: A-first (4 gld16 in ph0), then B (2/phase), so the
// single counted vmcnt(8) at step-end (before the last barrier) drains
// exactly next-buffer A while leaving all 8 B loads in flight (compiler
// inserts per-use waits for B).  Never vmcnt(0) mid-loop.  Accumulation
// order identical to r3 -> scores bit-identical.
__global__ __launch_bounds__(256, 2) void vq_mfma(
    const uint32_t* __restrict__ A_hi32,
    const uint32_t* __restrict__ A_lo32,
    const uint32_t* __restrict__ B_hi32,
    const uint32_t* __restrict__ B_lo32,
    const float* __restrict__ enorm,
    unsigned long long* __restrict__ best64)
{
    __shared__ __align__(16) _Float16 Abuf[2][2][4096];  // [buf][hi/lo][128x32] 32 KiB

    const int lane = threadIdx.x & 63;
    const int w    = threadIdx.x >> 6;   // 0..3
    const int q    = lane >> 4;
    const int c16  = lane & 15;
    const int bb   = blockIdx.x;
    const int xcd  = bb & 7;
    const int slot = bb >> 3;
    const int g    = (slot >> 2) * 8 + xcd;   // token group 0..255
    const int cq   = slot & 3;                // code quarter 0..3
    const int t0   = g * 128;
    const int cb   = cq * 256;
    const int lane4 = lane >> 2;
    // source-side swizzle: chunk c of row r lands at LDS slot c ^ ((r>>1)&3)
    const int dd8s  = ((lane & 3) ^ ((lane >> 3) & 3)) * 8;
    const int qs    = q ^ ((c16 >> 1) & 3);

    // staging role: wave w stages matrix (w>>1), row-blocks (w&1)*4 + s
    const uint32_t* const sA = (w >> 1) ? A_lo32 : A_hi32;
    const int r16b = (w & 1) * 4;

    // per-wave code slice: codes cb + w*64 + j*16 + c16 (fragment-packed B)
    float en[4];
    const uint32_t* bph[4];
    const uint32_t* bpl[4];
#pragma unroll
    for (int j = 0; j < 4; ++j) {
        const int code = cb + w * 64 + j * 16 + c16;
        en[j]  = enorm[code];
        const int cgj = (cb >> 4) + w * 4 + j;
        bph[j] = B_hi32 + cgj * 2048 + c16 * 16 + q * 4;
        bpl[j] = B_lo32 + cgj * 2048 + c16 * 16 + q * 4;
    }

    floatx4 acc[8][4];
#pragma unroll
    for (int i = 0; i < 8; ++i)
#pragma unroll
        for (int j = 0; j < 4; ++j)
            acc[i][j] = (floatx4){0.f, 0.f, 0.f, 0.f};

    half8 bh[2][4], bl[2][4];

    auto STAGE_A = [&](int step) {   // 4 gld16 (wave's A quarter of next tile)
        uint32_t* dst = (uint32_t*)(&Abuf[step & 1][w >> 1][0]);
        const int srcoff = (step * 32 + dd8s) >> 1;
#pragma unroll
        for (int s = 0; s < 4; ++s) {
            const int r16 = r16b + s;
            gld16(dst + r16 * 256, sA + (t0 + r16 * 16 + lane4) * 128 + srcoff);
        }
    };
    auto LOAD_B1 = [&](int step, int j, half8* h, half8* l) {
        h[j] = *(const half8*)(bph[j] + step * 256);
        l[j] = *(const half8*)(bpl[j] + step * 256);
    };

    // prologue: A(0) first, then B(0) (FIFO order matters for vmcnt math)
    STAGE_A(0);
#pragma unroll
    for (int j = 0; j < 4; ++j) LOAD_B1(0, j, bh[0], bl[0]);
    asm volatile("s_waitcnt vmcnt(8)" ::: "memory");   // A(0) staged
    __builtin_amdgcn_s_barrier();
    asm volatile("" ::: "memory");

#pragma unroll
    for (int dc = 0; dc < 8; ++dc) {
        const int cur = dc & 1;
        const int nxt = cur ^ 1;
        const _Float16* pH = &Abuf[cur][0][0];
        const _Float16* pL = &Abuf[cur][1][0];

#pragma unroll
        for (int ph = 0; ph < 4; ++ph) {
            // ds-load this phase's 2 token-rows (hi+lo frags)
            half8 aH[2], aL[2];
#pragma unroll
            for (int r = 0; r < 2; ++r) {
                const int i = ph * 2 + r;
                const int off = (i * 16 + c16) * 32 + qs * 8;
                aH[r] = *(const half8*)(pH + off);
                aL[r] = *(const half8*)(pL + off);
            }
            // issue next-step loads: all A in ph0 (FIFO-first), B 2/phase
            if (dc < 7) {
                if (ph == 0) STAGE_A(dc + 1);
                LOAD_B1(dc + 1, ph, bh[nxt], bl[nxt]);
            }
            __builtin_amdgcn_s_barrier();
            asm volatile("" ::: "memory");
            __builtin_amdgcn_s_setprio(1);
#pragma unroll
            for (int r = 0; r < 2; ++r) {
                const int i = ph * 2 + r;
#pragma unroll
                for (int j = 0; j < 4; ++j) {
                    acc[i][j] = __builtin_amdgcn_mfma_f32_16x16x32_f16(aH[r], bh[cur][j], acc[i][j], 0, 0, 0);
                    acc[i][j] = __builtin_amdgcn_mfma_f32_16x16x32_f16(aH[r], bl[cur][j], acc[i][j], 0, 0, 0);
                    acc[i][j] = __builtin_amdgcn_mfma_f32_16x16x32_f16(aL[r], bh[cur][j], acc[i][j], 0, 0, 0);
                }
            }
            __builtin_amdgcn_s_setprio(0);
            asm volatile("" ::: "memory");
            if (ph == 3) {
                // step-end: drain next-step A (leaves B(dc+1)'s 8 in flight)
                asm volatile("s_waitcnt vmcnt(8)" ::: "memory");
            }
            __builtin_amdgcn_s_barrier();
        }
    }

    // ---- epilogue: packed u64 (encf(score)<<32 | code) argmin ----
    unsigned long long best[32];
#pragma unroll
    for (int sl = 0; sl < 32; ++sl) best[sl] = ~0ULL;
#pragma unroll
    for (int j = 0; j < 4; ++j) {
        const unsigned int code = (unsigned int)(cb + w * 64 + j * 16 + c16);
        const float enj = en[j];
#pragma unroll
        for (int i = 0; i < 8; ++i)
#pragma unroll
            for (int r = 0; r < 4; ++r) {
                float sc = enj - 2.0f * acc[i][j][r];
                unsigned long long key =
                    ((unsigned long long)encf(sc) << 32) | code;
                int sl = i * 4 + r;
                if (key < best[sl]) best[sl] = key;
            }
    }
    // butterfly min across the 16 c16-lanes sharing each token
#pragma unroll
    for (int sl = 0; sl < 32; ++sl) {
        unsigned long long v = best[sl];
#pragma unroll
        for (int mm = 1; mm < 16; mm <<= 1) {
            unsigned long long o = __shfl_xor(v, mm);
            if (o < v) v = o;
        }
        if (c16 == (sl & 15)) {
            int tok = t0 + (sl >> 2) * 16 + q * 4 + (sl & 3);
            atomicMin(&best64[tok], v);
        }
    }
}

// ---- merge: decode best64 -> idx/cs/loss, write zq via float4 gathers ----
// loss = sum_t ( ||z_t||^2 + score_t ), score decoded exactly from the key.
__global__ __launch_bounds__(256) void merge_zq(
    const unsigned long long* __restrict__ best64,
    const float* __restrict__ embed,
    float* __restrict__ out_zq,
    float* __restrict__ out_idx /* = znorm stash, read before overwrite */,
    float* __restrict__ cs,
    float* __restrict__ loss_sum)
{
    __shared__ int sidx[64];
    const int tid = threadIdx.x;
    const int lane = tid & 63;
    const int w = tid >> 6;
    const int t0 = blockIdx.x * 64;

    if (tid < 64) {
        unsigned long long key = best64[t0 + tid];
        int code = (int)(unsigned int)(key & 0xffffffffULL);
        float sc = decf((unsigned int)(key >> 32));
        float zn = out_idx[t0 + tid];       // znorm stash (read first!)
        sidx[tid] = code;
        out_idx[t0 + tid] = (float)code;
        atomicAdd(&cs[code], 1.0f);
        float val = zn + sc;                 // ~ ||z_t - e_code||^2
        for (int off = 32; off > 0; off >>= 1) val += __shfl_down(val, off);
        if (lane == 0) atomicAdd(loss_sum, val);
    }
    __syncthreads();

    const int b_idx = t0 >> 10;
    const int hw0   = t0 & 1023;
    const int zbase = b_idx * 262144 + hw0;
    const int ka = sidx[lane];
    const float* erow = embed + ka * 256;
    for (int dq = w; dq < 64; dq += 4) {
        float4 e4 = *(const float4*)(erow + dq * 4);
        out_zq[zbase + (dq * 4 + 0) * 1024 + lane] = e4.x;
        out_zq[zbase + (dq * 4 + 1) * 1024 + lane] = e4.y;
        out_zq[zbase + (dq * 4 + 2) * 1024 + lane] = e4.z;
        out_zq[zbase + (dq * 4 + 3) * 1024 + lane] = e4.w;
    }
}

// ---- finalize: loss, new_cluster, csnorm, prefix-scan (wave shuffles) ----
__global__ void vq_finalize_small(const float* __restrict__ cluster_size,
                                  const float* __restrict__ cs,
                                  const float* __restrict__ loss_sum,
                                  float* __restrict__ out_loss,
                                  float* __restrict__ out_ncs,
                                  float* __restrict__ csnorm,
                                  int* __restrict__ offsets,
                                  int* __restrict__ cursor)
{
    __shared__ float wsum[16];
    __shared__ float wncs[16];
    __shared__ float stot[1];
    const int k = threadIdx.x;
    const int lane = k & 63;
    const int wv = k >> 6;
    float cnt = cs[k];
    float ncs = cluster_size[k] * DECAY + OMDECAY * cnt;
    out_ncs[k] = ncs;
    float sc = cnt;
#pragma unroll
    for (int d = 1; d < 64; d <<= 1) {
        float up = __shfl_up(sc, d);
        if (lane >= d) sc += up;
    }
    if (lane == 63) wsum[wv] = sc;
    float ns = ncs;
    for (int off = 32; off > 0; off >>= 1) ns += __shfl_down(ns, off);
    if (lane == 0) wncs[wv] = ns;
    __syncthreads();
    if (wv == 0) {
        float v = (lane < 16) ? wsum[lane] : 0.f;
#pragma unroll
        for (int d = 1; d < 16; d <<= 1) {
            float up = __shfl_up(v, d);
            if (lane >= d) v += up;
        }
        if (lane < 16) wsum[lane] = v;
    } else if (wv == 1) {
        float t = (lane < 16) ? wncs[lane] : 0.f;
        for (int off = 32; off > 0; off >>= 1) t += __shfl_down(t, off);
        if (lane == 0) stot[0] = t;
    }
    __syncthreads();
    float incl = sc + (wv ? wsum[wv - 1] : 0.f);
    int excl = __float2int_rn(incl - cnt);
    offsets[k] = excl;
    cursor[k]  = excl;
    float n = stot[0];
    csnorm[k] = (ncs + EPSV) / (n + 1024.0f * EPSV) * n;
    if (k == 0) out_loss[0] = loss_sum[0] / 8388608.0f;
}

// ---- counting-sort scatter + es zeroing ----
__global__ void scatter_perm(const float* __restrict__ out_idx,
                             int* __restrict__ cursor,
                             int* __restrict__ perm,
                             float* __restrict__ es)
{
    int t = blockIdx.x * 256 + threadIdx.x;
#pragma unroll
    for (int i = 0; i < 8; ++i) es[t + i * 32768] = 0.f;
    int code = (int)out_idx[t];
    int pos = atomicAdd(&cursor[code], 1);
    perm[pos] = t;
}

// ---- chunked segmented sum over the SORTED token list ----
__global__ void es_sum(const uint32_t* __restrict__ A_hi32,
                       const uint32_t* __restrict__ A_lo32,
                       const int* __restrict__ perm,
                       const float* __restrict__ out_idx,
                       float* __restrict__ es)
{
    __shared__ int sperm[32];
    __shared__ int scode[32];
    const int base = blockIdx.x * 32;
    const int tid = threadIdx.x;
    const int j = tid & 127;
    const uint32_t* __restrict__ A = (tid >> 7) ? A_lo32 : A_hi32;
    if (tid < 32) {
        int t = perm[base + tid];
        sperm[tid] = t;
        scode[tid] = (int)out_idx[t];
    }
    __syncthreads();

    float s0 = 0.f, s1 = 0.f;
    int cur = scode[0];
    uint32_t pu[2];
    pu[0] = A[sperm[0] * 128 + j];
    pu[1] = A[sperm[1] * 128 + j];
#pragma unroll
    for (int i = 0; i < 32; ++i) {
        uint32_t u = pu[i & 1];
        if (i + 2 < 32) pu[i & 1] = A[sperm[i + 2] * 128 + j];
        int code = scode[i];
        if (code != cur) {
            atomicAdd(&es[cur * 256 + 2 * j],     s0);
            atomicAdd(&es[cur * 256 + 2 * j + 1], s1);
            s0 = 0.f; s1 = 0.f; cur = code;
        }
        s0 += (float)__builtin_bit_cast(_Float16, (unsigned short)(u & 0xffffu));
        s1 += (float)__builtin_bit_cast(_Float16, (unsigned short)(u >> 16));
    }
    atomicAdd(&es[cur * 256 + 2 * j],     s0);
    atomicAdd(&es[cur * 256 + 2 * j + 1], s1);
}

// ---- EMA finalize for embed_avg / embed (overwrites best64 scratch) ----
__global__ void finalize_embed(const float* __restrict__ embed_avg,
                               const float* __restrict__ es,
                               const float* __restrict__ csnorm,
                               float* __restrict__ out_embed,
                               float* __restrict__ out_nea)
{
    int idx = blockIdx.x * 256 + threadIdx.x;
    int k = idx >> 8;
    float nea = embed_avg[idx] * DECAY + OMDECAY * es[idx];
    out_nea[idx] = nea;
    out_embed[idx] = nea / csnorm[k];
}

extern "C" void kernel_launch(void* const* d_in, const int* in_sizes, int n_in,
                              void* d_out, int out_size, void* d_ws, size_t ws_size,
                              hipStream_t stream) {
    const float* z            = (const float*)d_in[0];
    const float* embed        = (const float*)d_in[1];
    const float* cluster_size = (const float*)d_in[2];
    const float* embed_avg    = (const float*)d_in[3];
    float* out = (float*)d_out;
    uint32_t* ws32 = (uint32_t*)d_ws;

    uint32_t* B_hi32 = ws32 + 0;
    uint32_t* B_lo32 = ws32 + 131072;
    uint32_t* A_hi32 = ws32 + 262144;
    uint32_t* A_lo32 = ws32 + 4456448;
    int* perm        = (int*)(ws32 + 8650752);
    int* offsets     = (int*)(ws32 + 8683520);
    int* cursor      = (int*)(ws32 + 8684544);
    float* cs        = (float*)(ws32 + 8912896);
    float* loss_sum  = (float*)(ws32 + 8913920);
    float* enorm     = (float*)(ws32 + 8914944);
    float* csnorm    = (float*)(ws32 + 8915968);
    float* es        = (float*)(ws32 + 0);        // reuses B_hi/B_lo after vq_mfma
    // best64 scratch overlays the new_embed output region (8-byte aligned)
    unsigned long long* best64 = (unsigned long long*)(out + 8421378);
    float* znstash = out + 8388608;               // overlays out_idx region

    prep_fused<<<2048, 256, 0, stream>>>(z, A_hi32, A_lo32, embed,
                                         (unsigned short*)B_hi32,
                                         (unsigned short*)B_lo32, enorm, cs,
                                         (uint32_t*)best64, znstash);
    vq_mfma<<<1024, 256, 0, stream>>>(A_hi32, A_lo32, B_hi32, B_lo32, enorm, best64);
    merge_zq<<<512, 256, 0, stream>>>(best64, embed,
                                      out, out + 8388608, cs, loss_sum);
    vq_finalize_small<<<1, 1024, 0, stream>>>(cluster_size, cs, loss_sum,
                                              out + 8421376, out + 8683521, csnorm,
                                              offsets, cursor);
    scatter_perm<<<128, 256, 0, stream>>>(out + 8388608, cursor, perm, es);
    es_sum<<<1024, 256, 0, stream>>>(A_hi32, A_lo32, perm, out + 8388608, es);
    finalize_embed<<<1024, 256, 0, stream>>>(embed_avg, es, csnorm,
                                             out + 8421377, out + 8684545);
}